// Round 1
// baseline (349.723 us; speedup 1.0000x reference)
//
#include <hip/hip_runtime.h>
#include <hip/hip_fp16.h>

#define CIN   64
#define COUT  128
#define HW    56
#define KK    3
#define LTAPS 576   // CIN * 9

// ---------------------------------------------------------------------------
// Kernel 1: build G[l][a][co] = (half) lut[a][ weight[co][l] ]
//   l = ci*9 + kh*3 + kw  (matches reference weight.reshape(Cout, Cin*K*K))
// ---------------------------------------------------------------------------
__global__ __launch_bounds__(256) void build_G(const int* __restrict__ weight,
                                               const float* __restrict__ lut,
                                               __half* __restrict__ G) {
    int idx = blockIdx.x * 256 + threadIdx.x;   // idx = (l*256 + a)*128 + co
    int co = idx & 127;
    int la = idx >> 7;
    int a  = la & 255;
    int l  = la >> 8;
    int w  = weight[co * LTAPS + l];
    G[idx] = __float2half(lut[a * 256 + w]);
}

// ---------------------------------------------------------------------------
// Kernel 2: main conv via pre-gathered rows.
// Block = 256 threads, one 4x4 spatial tile of one batch image, all 128 co.
//   q = tid & 31  -> covers co = 4q .. 4q+3 (half4 = 8B load per row)
//   g = tid >> 5  -> pixel pair (2g, 2g+1) of the 16-pixel tile
// Patch codes staged in LDS as u8 (pad -> code 0, matching reference).
// ---------------------------------------------------------------------------
__global__ __launch_bounds__(256) void conv_lut(const int* __restrict__ input,
                                                const __half* __restrict__ G,
                                                const float* __restrict__ bias,
                                                float* __restrict__ out) {
    __shared__ unsigned char sA[CIN * 36];   // [ci][6][6]

    int bx = blockIdx.x;
    int b  = bx / 196;          // 196 = 14*14 tiles per image
    int r  = bx % 196;
    int y0 = (r / 14) * 4;
    int x0 = (r % 14) * 4;

    int tid = threadIdx.x;

    // ---- stage 6x6 patch codes per ci (zero-pad = code 0) ----
    for (int i = tid; i < CIN * 36; i += 256) {
        int ci = i / 36, rr = i % 36;
        int yy = y0 + rr / 6 - 1;
        int xx = x0 + rr % 6 - 1;
        int v = 0;
        if (yy >= 0 && yy < HW && xx >= 0 && xx < HW)
            v = input[((b * CIN + ci) * HW + yy) * HW + xx];
        sA[i] = (unsigned char)v;
    }
    __syncthreads();

    const int q  = tid & 31;
    const int g  = tid >> 5;
    const int qv = q * 4;              // co base
    const int p0 = g * 2, p1 = p0 + 1; // two pixels of the 4x4 tile
    const int py0 = p0 >> 2, px0 = p0 & 3;
    const int py1 = p1 >> 2, px1 = p1 & 3;
    const int pb0 = py0 * 6 + px0;
    const int pb1 = py1 * 6 + px1;

    float acc0[4] = {0.f, 0.f, 0.f, 0.f};
    float acc1[4] = {0.f, 0.f, 0.f, 0.f};

    const int off[9] = {0, 1, 2, 6, 7, 8, 12, 13, 14};  // kh*6 + kw

    for (int ci = 0; ci < CIN; ++ci) {
        const int cbase = ci * 36;
#pragma unroll
        for (int t = 0; t < 9; ++t) {
            const int l = ci * 9 + t;
            const int a0 = sA[cbase + pb0 + off[t]];
            const int a1 = sA[cbase + pb1 + off[t]];
            const __half* Gl = G + (size_t)l * (256 * 128);
            uint2 d0 = *(const uint2*)(Gl + a0 * 128 + qv);
            uint2 d1 = *(const uint2*)(Gl + a1 * 128 + qv);
            {
                __half2 h0 = *reinterpret_cast<__half2*>(&d0.x);
                __half2 h1 = *reinterpret_cast<__half2*>(&d0.y);
                float2 f0 = __half22float2(h0);
                float2 f1 = __half22float2(h1);
                acc0[0] += f0.x; acc0[1] += f0.y;
                acc0[2] += f1.x; acc0[3] += f1.y;
            }
            {
                __half2 h0 = *reinterpret_cast<__half2*>(&d1.x);
                __half2 h1 = *reinterpret_cast<__half2*>(&d1.y);
                float2 f0 = __half22float2(h0);
                float2 f1 = __half22float2(h1);
                acc1[0] += f0.x; acc1[1] += f0.y;
                acc1[2] += f1.x; acc1[3] += f1.y;
            }
        }
    }

    // ---- epilogue: bias + store ----
    const int oh0 = y0 + py0, ow0 = x0 + px0;
    const int oh1 = y0 + py1, ow1 = x0 + px1;
#pragma unroll
    for (int j = 0; j < 4; ++j) {
        const int co = qv + j;
        const float bb = bias[co];
        out[((size_t)(b * COUT + co) * HW + oh0) * HW + ow0] = acc0[j] + bb;
        out[((size_t)(b * COUT + co) * HW + oh1) * HW + ow1] = acc1[j] + bb;
    }
}

// ---------------------------------------------------------------------------
// Fallback (ws too small): gather lut directly, fp32 exact.
// ---------------------------------------------------------------------------
__global__ __launch_bounds__(256) void conv_direct(const int* __restrict__ input,
                                                   const int* __restrict__ weight,
                                                   const float* __restrict__ lut,
                                                   const float* __restrict__ bias,
                                                   float* __restrict__ out) {
    __shared__ unsigned char sA[CIN * 36];

    int bx = blockIdx.x;
    int b  = bx / 196;
    int r  = bx % 196;
    int y0 = (r / 14) * 4;
    int x0 = (r % 14) * 4;

    int tid = threadIdx.x;
    for (int i = tid; i < CIN * 36; i += 256) {
        int ci = i / 36, rr = i % 36;
        int yy = y0 + rr / 6 - 1;
        int xx = x0 + rr % 6 - 1;
        int v = 0;
        if (yy >= 0 && yy < HW && xx >= 0 && xx < HW)
            v = input[((b * CIN + ci) * HW + yy) * HW + xx];
        sA[i] = (unsigned char)v;
    }
    __syncthreads();

    const int q  = tid & 31;
    const int g  = tid >> 5;
    const int qv = q * 4;
    const int p0 = g * 2, p1 = p0 + 1;
    const int py0 = p0 >> 2, px0 = p0 & 3;
    const int py1 = p1 >> 2, px1 = p1 & 3;
    const int pb0 = py0 * 6 + px0;
    const int pb1 = py1 * 6 + px1;

    float acc0[4] = {0.f, 0.f, 0.f, 0.f};
    float acc1[4] = {0.f, 0.f, 0.f, 0.f};
    const int off[9] = {0, 1, 2, 6, 7, 8, 12, 13, 14};

    for (int ci = 0; ci < CIN; ++ci) {
        const int cbase = ci * 36;
#pragma unroll
        for (int t = 0; t < 9; ++t) {
            const int l = ci * 9 + t;
            const int a0 = sA[cbase + pb0 + off[t]];
            const int a1 = sA[cbase + pb1 + off[t]];
#pragma unroll
            for (int j = 0; j < 4; ++j) {
                const int w = weight[(qv + j) * LTAPS + l];
                acc0[j] += lut[a0 * 256 + w];
                acc1[j] += lut[a1 * 256 + w];
            }
        }
    }

    const int oh0 = y0 + py0, ow0 = x0 + px0;
    const int oh1 = y0 + py1, ow1 = x0 + px1;
#pragma unroll
    for (int j = 0; j < 4; ++j) {
        const int co = qv + j;
        const float bb = bias[co];
        out[((size_t)(b * COUT + co) * HW + oh0) * HW + ow0] = acc0[j] + bb;
        out[((size_t)(b * COUT + co) * HW + oh1) * HW + ow1] = acc1[j] + bb;
    }
}

// ---------------------------------------------------------------------------
extern "C" void kernel_launch(void* const* d_in, const int* in_sizes, int n_in,
                              void* d_out, int out_size, void* d_ws, size_t ws_size,
                              hipStream_t stream) {
    const int*   input  = (const int*)d_in[0];
    const int*   weight = (const int*)d_in[1];
    const float* lut    = (const float*)d_in[2];
    const float* bias   = (const float*)d_in[3];
    float*       out    = (float*)d_out;

    const size_t g_bytes = (size_t)LTAPS * 256 * 128 * sizeof(__half);  // ~37.7 MB
    const int    grid_main = 8 * 14 * 14;  // 1568 blocks

    if (ws_size >= g_bytes) {
        __half* G = (__half*)d_ws;
        build_G<<<(LTAPS * 256 * 128) / 256, 256, 0, stream>>>(weight, lut, G);
        conv_lut<<<grid_main, 256, 0, stream>>>(input, G, bias, out);
    } else {
        conv_direct<<<grid_main, 256, 0, stream>>>(input, weight, lut, bias, out);
    }
}

// Round 2
// 305.196 us; speedup vs baseline: 1.1459x; 1.1459x over previous
//
#include <hip/hip_runtime.h>
#include <hip/hip_fp16.h>

#define CIN   64
#define COUT  128
#define HW    56
#define LTAPS 576   // CIN * 9

// ---------------------------------------------------------------------------
// Kernel 1: build G[l][a][co] = (half) lut[a][ weight[co][l] ]
// One thread per (l, a, co-pair); writes half2 (4 B coalesced).
// ---------------------------------------------------------------------------
__global__ __launch_bounds__(256) void build_G(const int* __restrict__ weight,
                                               const float* __restrict__ lut,
                                               __half2* __restrict__ G2) {
    int idx = blockIdx.x * 256 + threadIdx.x;   // idx = (l*256 + a)*64 + co2
    int c2 = idx & 63;
    int la = idx >> 6;
    int a  = la & 255;
    int l  = la >> 8;
    int co = c2 * 2;
    int w0 = weight[co * LTAPS + l];
    int w1 = weight[(co + 1) * LTAPS + l];
    const float* lr = lut + a * 256;
    G2[idx] = __floats2half2_rn(lr[w0], lr[w1]);
}

// ---------------------------------------------------------------------------
// Kernel 2: main conv via pre-gathered rows.
// Block = 256 threads, one 4x4 spatial tile of one image, all 128 co.
//   q = tid & 15  -> co = 8q .. 8q+7  (one 16 B dwordx4 load per row)
//   g = tid >> 4  -> pixel g of the 16-pixel tile
// 16 lanes x 16 B = full 256 B row, coalesced. Packed fp16 accumulation,
// flushed to fp32 every 8 ci (72 taps/group).
// ---------------------------------------------------------------------------
__global__ __launch_bounds__(256) void conv_lut(const int* __restrict__ input,
                                                const __half* __restrict__ G,
                                                const float* __restrict__ bias,
                                                float* __restrict__ out) {
    __shared__ unsigned char sA[CIN * 36];   // [ci][6][6]

    int bx = blockIdx.x;
    int b  = bx / 196;          // 196 = 14*14 tiles per image
    int r  = bx % 196;
    int y0 = (r / 14) * 4;
    int x0 = (r % 14) * 4;

    int tid = threadIdx.x;

    // ---- stage 6x6 patch codes per ci (zero-pad = code 0) ----
    for (int i = tid; i < CIN * 36; i += 256) {
        int ci = i / 36, rr = i % 36;
        int yy = y0 + rr / 6 - 1;
        int xx = x0 + rr % 6 - 1;
        int v = 0;
        if (yy >= 0 && yy < HW && xx >= 0 && xx < HW)
            v = input[((b * CIN + ci) * HW + yy) * HW + xx];
        sA[i] = (unsigned char)v;
    }
    __syncthreads();

    const int q  = tid & 15;           // co octet
    const int g  = tid >> 4;           // pixel 0..15
    const int py = g >> 2, px = g & 3;
    const int pb = py * 6 + px;        // top-left of 3x3 window in 6x6 patch
    const int qb = q * 16;             // byte offset within 256 B row

    float accf[8] = {0.f, 0.f, 0.f, 0.f, 0.f, 0.f, 0.f, 0.f};

    for (int ci0 = 0; ci0 < CIN; ci0 += 8) {
        __half2 a0 = __float2half2_rn(0.f);
        __half2 a1 = __float2half2_rn(0.f);
        __half2 a2 = __float2half2_rn(0.f);
        __half2 a3 = __float2half2_rn(0.f);
#pragma unroll
        for (int cid = 0; cid < 8; ++cid) {
            const int ci = ci0 + cid;
            const unsigned char* sc = sA + ci * 36 + pb;
            const char* Gl = (const char*)G + ((size_t)(ci * 9) << 16);
#pragma unroll
            for (int t = 0; t < 9; ++t) {
                const int toff = (t / 3) * 6 + (t % 3);         // kh*6+kw
                const int a = sc[toff];
                uint4 d = *(const uint4*)(Gl + ((size_t)t << 16) + (a << 8) + qb);
                const __half2* h = (const __half2*)&d;
                a0 += h[0]; a1 += h[1]; a2 += h[2]; a3 += h[3];
            }
        }
        float2 f;
        f = __half22float2(a0); accf[0] += f.x; accf[1] += f.y;
        f = __half22float2(a1); accf[2] += f.x; accf[3] += f.y;
        f = __half22float2(a2); accf[4] += f.x; accf[5] += f.y;
        f = __half22float2(a3); accf[6] += f.x; accf[7] += f.y;
    }

    // ---- epilogue: bias + store ----
    const int oh  = y0 + py, ow = x0 + px;
    const int cob = q * 8;
#pragma unroll
    for (int j = 0; j < 8; ++j) {
        const int co = cob + j;
        out[((size_t)(b * COUT + co) * HW + oh) * HW + ow] = accf[j] + bias[co];
    }
}

// ---------------------------------------------------------------------------
// Fallback (ws too small): gather lut directly, fp32 exact.
// ---------------------------------------------------------------------------
__global__ __launch_bounds__(256) void conv_direct(const int* __restrict__ input,
                                                   const int* __restrict__ weight,
                                                   const float* __restrict__ lut,
                                                   const float* __restrict__ bias,
                                                   float* __restrict__ out) {
    __shared__ unsigned char sA[CIN * 36];

    int bx = blockIdx.x;
    int b  = bx / 196;
    int r  = bx % 196;
    int y0 = (r / 14) * 4;
    int x0 = (r % 14) * 4;

    int tid = threadIdx.x;
    for (int i = tid; i < CIN * 36; i += 256) {
        int ci = i / 36, rr = i % 36;
        int yy = y0 + rr / 6 - 1;
        int xx = x0 + rr % 6 - 1;
        int v = 0;
        if (yy >= 0 && yy < HW && xx >= 0 && xx < HW)
            v = input[((b * CIN + ci) * HW + yy) * HW + xx];
        sA[i] = (unsigned char)v;
    }
    __syncthreads();

    const int q  = tid & 31;
    const int g  = tid >> 5;
    const int qv = q * 4;
    const int p0 = g * 2, p1 = p0 + 1;
    const int py0 = p0 >> 2, px0 = p0 & 3;
    const int py1 = p1 >> 2, px1 = p1 & 3;
    const int pb0 = py0 * 6 + px0;
    const int pb1 = py1 * 6 + px1;

    float acc0[4] = {0.f, 0.f, 0.f, 0.f};
    float acc1[4] = {0.f, 0.f, 0.f, 0.f};
    const int off[9] = {0, 1, 2, 6, 7, 8, 12, 13, 14};

    for (int ci = 0; ci < CIN; ++ci) {
        const int cbase = ci * 36;
#pragma unroll
        for (int t = 0; t < 9; ++t) {
            const int l = ci * 9 + t;
            const int a0 = sA[cbase + pb0 + off[t]];
            const int a1 = sA[cbase + pb1 + off[t]];
#pragma unroll
            for (int j = 0; j < 4; ++j) {
                const int w = weight[(qv + j) * LTAPS + l];
                acc0[j] += lut[a0 * 256 + w];
                acc1[j] += lut[a1 * 256 + w];
            }
        }
    }

    const int oh0 = y0 + py0, ow0 = x0 + px0;
    const int oh1 = y0 + py1, ow1 = x0 + px1;
#pragma unroll
    for (int j = 0; j < 4; ++j) {
        const int co = qv + j;
        const float bb = bias[co];
        out[((size_t)(b * COUT + co) * HW + oh0) * HW + ow0] = acc0[j] + bb;
        out[((size_t)(b * COUT + co) * HW + oh1) * HW + ow1] = acc1[j] + bb;
    }
}

// ---------------------------------------------------------------------------
extern "C" void kernel_launch(void* const* d_in, const int* in_sizes, int n_in,
                              void* d_out, int out_size, void* d_ws, size_t ws_size,
                              hipStream_t stream) {
    const int*   input  = (const int*)d_in[0];
    const int*   weight = (const int*)d_in[1];
    const float* lut    = (const float*)d_in[2];
    const float* bias   = (const float*)d_in[3];
    float*       out    = (float*)d_out;

    const size_t g_bytes = (size_t)LTAPS * 256 * 128 * sizeof(__half);  // ~37.7 MB
    const int    grid_main = 8 * 14 * 14;  // 1568 blocks

    if (ws_size >= g_bytes) {
        __half2* G2 = (__half2*)d_ws;
        build_G<<<LTAPS * 64, 256, 0, stream>>>(weight, lut, G2);
        conv_lut<<<grid_main, 256, 0, stream>>>(input, (const __half*)d_ws, bias, out);
    } else {
        conv_direct<<<grid_main, 256, 0, stream>>>(input, weight, lut, bias, out);
    }
}